// Round 13
// baseline (324.006 us; speedup 1.0000x reference)
//
#include <hip/hip_runtime.h>
#include <math.h>

#define N_NODES 1024
#define B_SZ 64
#define GNH 4096     // half-width: b*64+c layout for X or S plane
#define KI 384       // 3*128
#define EDIM 16

typedef _Float16 half8_t __attribute__((ext_vector_type(8)));
typedef float f32x4 __attribute__((ext_vector_type(4)));

__device__ __forceinline__ unsigned short f2h(float f) {
    _Float16 h = (_Float16)f;
    return *(unsigned short*)&h;
}
__device__ __forceinline__ float h2f(unsigned short u) {
    _Float16 h = *(_Float16*)&u;
    return (float)h;
}
__device__ __forceinline__ float sigmoidf_(float v) {
    return 1.f / (1.f + __expf(-v));
}
// async global->LDS, 16B per lane; lds base must be wave-uniform.
__device__ __forceinline__ void load_lds16(const void* g, void* l) {
    __builtin_amdgcn_global_load_lds(
        (const __attribute__((address_space(1))) void*)g,
        (__attribute__((address_space(3))) void*)l, 16, 0, 0);
}

// ---------------------------------------------------------------------------
// A = softmax(relu(E E^T)) row-wise -> Ah[n][m]  (fp16, coalesced only)
// ---------------------------------------------------------------------------
__global__ __launch_bounds__(256) void compute_A_kernel(
    const float* __restrict__ E, unsigned short* __restrict__ Ah) {
    __shared__ float red[256];
    const int tid = threadIdx.x;
    const int n = blockIdx.x;
    float en[EDIM];
#pragma unroll
    for (int e = 0; e < EDIM; ++e) en[e] = E[n * EDIM + e];
    float logit[4], lmax = -1e30f;
#pragma unroll
    for (int j = 0; j < 4; ++j) {
        const int m = tid + j * 256;
        float d = 0.f;
#pragma unroll
        for (int e = 0; e < EDIM; ++e) d += en[e] * E[m * EDIM + e];
        d = fmaxf(d, 0.f);
        logit[j] = d;
        lmax = fmaxf(lmax, d);
    }
    red[tid] = lmax;
    __syncthreads();
    for (int s = 128; s > 0; s >>= 1) {
        if (tid < s) red[tid] = fmaxf(red[tid], red[tid + s]);
        __syncthreads();
    }
    lmax = red[0];
    __syncthreads();
    float ex[4], lsum = 0.f;
#pragma unroll
    for (int j = 0; j < 4; ++j) {
        ex[j] = __expf(logit[j] - lmax);
        lsum += ex[j];
    }
    red[tid] = lsum;
    __syncthreads();
    for (int s = 128; s > 0; s >>= 1) {
        if (tid < s) red[tid] += red[tid + s];
        __syncthreads();
    }
    const float inv = 1.f / red[0];
#pragma unroll
    for (int j = 0; j < 4; ++j)
        Ah[n * N_NODES + tid + j * 256] = f2h(ex[j] * inv);
}

// ---------------------------------------------------------------------------
// Fused build: TX0/TS0 (row-major, direct) + TX0T/TS0T (via LDS transpose).
// grid (16 n-tiles, 64 b).
// ---------------------------------------------------------------------------
__global__ __launch_bounds__(256) void build_T0_all_kernel(
    const float* __restrict__ x, const float* __restrict__ state,
    unsigned short* __restrict__ TX0, unsigned short* __restrict__ TS0,
    unsigned short* __restrict__ TX0T, unsigned short* __restrict__ TS0T) {
    __shared__ unsigned short Lx[64 * 72];   // [c][nl], pad 72 (16B rows)
    __shared__ unsigned short Lss[64 * 72];
    const int tid = threadIdx.x;
    const int n0 = blockIdx.x * 64;
    const int b = blockIdx.y;
#pragma unroll
    for (int t = 0; t < 16; ++t) {
        const int id = t * 256 + tid;
        const int nl = id >> 6;
        const int c = id & 63;
        const float xv = x[((size_t)b * N_NODES + n0 + nl) * 64 + c];
        const float sv = state[((size_t)b * N_NODES + n0 + nl) * 64 + c];
        const unsigned short xh = f2h(xv), sh = f2h(sv);
        TX0[(size_t)(n0 + nl) * GNH + b * 64 + c] = xh;
        TS0[(size_t)(n0 + nl) * GNH + b * 64 + c] = sh;
        Lx[c * 72 + nl] = xh;
        Lss[c * 72 + nl] = sh;
    }
    __syncthreads();
#pragma unroll
    for (int t = 0; t < 2; ++t) {
        const int id = t * 256 + tid;
        const int c = id >> 3;
        const int n8 = id & 7;
        uint4 xv = *(const uint4*)&Lx[c * 72 + n8 * 8];
        uint4 sv = *(const uint4*)&Lss[c * 72 + n8 * 8];
        *(uint4*)&TX0T[(size_t)(b * 64 + c) * N_NODES + n0 + n8 * 8] = xv;
        *(uint4*)&TS0T[(size_t)(b * 64 + c) * N_NODES + n0 + n8 * 8] = sv;
    }
}

// ---------------------------------------------------------------------------
// Generic fp16 transpose: dst[c][1024] = src[r][W], 64x64 tiles.
// ---------------------------------------------------------------------------
__global__ __launch_bounds__(256) void transpose16_kernel(
    const unsigned short* __restrict__ src, unsigned short* __restrict__ dst,
    int W) {
    __shared__ unsigned short Ls[64 * 72];
    const int tid = threadIdx.x;
    const int r0 = blockIdx.x * 64;
    const int c0 = blockIdx.y * 64;
#pragma unroll
    for (int t = 0; t < 2; ++t) {
        const int id = t * 256 + tid;
        const int row = id >> 3;
        const int c8 = id & 7;
        uint4 v = *(const uint4*)&src[(size_t)(r0 + row) * W + c0 + c8 * 8];
        const unsigned short* vp = (const unsigned short*)&v;
#pragma unroll
        for (int j = 0; j < 8; ++j) Ls[(c8 * 8 + j) * 72 + row] = vp[j];
    }
    __syncthreads();
#pragma unroll
    for (int t = 0; t < 2; ++t) {
        const int id = t * 256 + tid;
        const int c = id >> 3;
        const int r8 = id & 7;
        uint4 v = *(const uint4*)&Ls[c * 72 + r8 * 8];
        *(uint4*)&dst[(size_t)(c0 + c) * N_NODES + r0 + r8 * 8] = v;
    }
}

// ---------------------------------------------------------------------------
// S2h[n][m] = 2 * sum_k Ah[n][k]*AhT[m][k] - (n==m)   (S2 = 2A^2 - I)
// ---------------------------------------------------------------------------
__global__ __launch_bounds__(256) void gemm_s2_kernel(
    const unsigned short* __restrict__ Ah,
    const unsigned short* __restrict__ AhT, unsigned short* __restrict__ S2h) {
    __shared__ unsigned short As[64 * 64];
    __shared__ unsigned short Bs[64 * 64];
    const int tid = threadIdx.x;
    const int wave = tid >> 6;
    const int lane = tid & 63;
    const int l15 = lane & 15;
    const int quad = lane >> 4;
    const int n0 = blockIdx.x * 64;
    const int m0 = blockIdx.y * 64;
    const int wn = wave * 16;
    const int lr = lane >> 3;
    const int lsw = (lane & 7) ^ lr;

    f32x4 acc[4] = {};
    for (int k0 = 0; k0 < N_NODES; k0 += 64) {
#pragma unroll
        for (int i = 0; i < 2; ++i) {
            const int rbase = (wave * 2 + i) * 8;
            load_lds16(&Ah[(size_t)(n0 + rbase + lr) * N_NODES + k0 + lsw * 8],
                       &As[rbase * 64]);
            load_lds16(&AhT[(size_t)(m0 + rbase + lr) * N_NODES + k0 + lsw * 8],
                       &Bs[rbase * 64]);
        }
        __syncthreads();
#pragma unroll
        for (int ks = 0; ks < 2; ++ks) {
            const int slot = ((ks * 4 + quad) ^ (l15 & 7)) * 8;
            const half8_t b = *(const half8_t*)&Bs[(wn + l15) * 64 + slot];
#pragma unroll
            for (int mi = 0; mi < 4; ++mi) {
                const half8_t a = *(const half8_t*)&As[(mi * 16 + l15) * 64 + slot];
                acc[mi] =
                    __builtin_amdgcn_mfma_f32_16x16x32_f16(a, b, acc[mi], 0, 0, 0);
            }
        }
        __syncthreads();
    }
#pragma unroll
    for (int mi = 0; mi < 4; ++mi) {
#pragma unroll
        for (int r = 0; r < 4; ++r) {
            const int n_g = n0 + mi * 16 + quad * 4 + r;
            const int m_g = m0 + wn + l15;
            const float v = 2.f * acc[mi][r] - (n_g == m_g ? 1.f : 0.f);
            S2h[(size_t)n_g * N_NODES + m_g] = f2h(v);
        }
    }
}

// ---------------------------------------------------------------------------
// Graph GEMM: 128x128 tile, BK=64, rows [A;S2]; cols X/S planes. 32 KB LDS.
// 1D grid, XCD-aware swizzle (xcd = id&7 owns contiguous column slab).
// ---------------------------------------------------------------------------
__global__ __launch_bounds__(256) void gemm_graph_kernel(
    const unsigned short* __restrict__ Ah,
    const unsigned short* __restrict__ S2h,
    const unsigned short* __restrict__ BTX,
    const unsigned short* __restrict__ BTS,
    unsigned short* __restrict__ T1X, unsigned short* __restrict__ T1S,
    unsigned short* __restrict__ T2X, unsigned short* __restrict__ T2S,
    int ysplit, int colsPerXcd) {
    __shared__ union {
        struct {
            unsigned short As[128 * 64];  // [m-local][k] swizzled (16 KB)
            unsigned short Bs[128 * 64];  // [col-local][k] swizzled (16 KB)
        } s;
        unsigned short Cs[64 * 136];      // epilogue repack (17.4 KB)
    } lds;
    const int tid = threadIdx.x;
    const int wave = tid >> 6;
    const int lane = tid & 63;
    const int l15 = lane & 15;
    const int quad = lane >> 4;
    const int wm = (wave >> 1) * 64;
    const int wn = (wave & 1) * 64;
    // XCD-locality swizzle
    const int id = blockIdx.x;
    const int xcd = id & 7;
    const int j = id >> 3;
    const int mrow0 = (j & 15) * 128;
    const int ytile = xcd * colsPerXcd + (j >> 4);
    const bool isA = mrow0 < N_NODES;
    const unsigned short* Asrc =
        (isA ? Ah : S2h) + (size_t)(mrow0 & 1023) * N_NODES;
    const bool isX = ytile < ysplit;
    const int col0 = (isX ? ytile : ytile - ysplit) * 128;
    const unsigned short* Bsrc =
        (isX ? BTX : BTS) + (size_t)col0 * N_NODES;
    unsigned short* OUT =
        (isA ? (isX ? T1X : T1S) : (isX ? T2X : T2S)) +
        (size_t)(mrow0 & 1023) * GNH + col0;
    const int lr = lane >> 3;
    const int lsw = (lane & 7) ^ lr;

    f32x4 acc[4][4] = {};

    for (int k0 = 0; k0 < N_NODES; k0 += 64) {
#pragma unroll
        for (int i = 0; i < 4; ++i) {
            const int rbase = (wave * 4 + i) * 8;
            load_lds16(&Asrc[(size_t)(rbase + lr) * N_NODES + k0 + lsw * 8],
                       &lds.s.As[rbase * 64]);
        }
#pragma unroll
        for (int i = 0; i < 4; ++i) {
            const int rbase = (wave * 4 + i) * 8;
            load_lds16(&Bsrc[(size_t)(rbase + lr) * N_NODES + k0 + lsw * 8],
                       &lds.s.Bs[rbase * 64]);
        }
        __syncthreads();
#pragma unroll
        for (int ks = 0; ks < 2; ++ks) {
            const int slot = ((ks * 4 + quad) ^ (l15 & 7)) * 8;
            half8_t a[4], b[4];
#pragma unroll
            for (int mi = 0; mi < 4; ++mi)
                a[mi] = *(const half8_t*)&lds.s
                             .As[(wm + mi * 16 + l15) * 64 + slot];
#pragma unroll
            for (int ni = 0; ni < 4; ++ni)
                b[ni] = *(const half8_t*)&lds.s
                             .Bs[(wn + ni * 16 + l15) * 64 + slot];
#pragma unroll
            for (int mi = 0; mi < 4; ++mi)
#pragma unroll
                for (int ni = 0; ni < 4; ++ni)
                    acc[mi][ni] = __builtin_amdgcn_mfma_f32_16x16x32_f16(
                        a[mi], b[ni], acc[mi][ni], 0, 0, 0);
        }
        __syncthreads();
    }

    // epilogue: two 64-row passes through 64x136 Cs -> coalesced uint4 stores
#pragma unroll
    for (int p = 0; p < 2; ++p) {
        if (p) __syncthreads();
        if ((wave >> 1) == p) {
#pragma unroll
            for (int mi = 0; mi < 4; ++mi)
#pragma unroll
                for (int ni = 0; ni < 4; ++ni)
#pragma unroll
                    for (int r = 0; r < 4; ++r) {
                        const int row = mi * 16 + quad * 4 + r;  // 0..63
                        const int col = wn + ni * 16 + l15;
                        lds.Cs[row * 136 + col] = f2h(acc[mi][ni][r]);
                    }
        }
        __syncthreads();
#pragma unroll
        for (int i = 0; i < 4; ++i) {
            const int id2 = i * 256 + tid;  // 0..1023
            const int row = id2 >> 4;       // 0..63
            const int c8 = id2 & 15;
            uint4 cv = *(const uint4*)&lds.Cs[row * 136 + c8 * 8];
            *(uint4*)&OUT[(size_t)(p * 64 + row) * GNH + c8 * 8] = cv;
        }
    }
}

// ---------------------------------------------------------------------------
// Dequant: Wt[n][o][ki] = sum_e E[n,e]*Wp[e][ki][o]  (fp16, k-contig)
// ---------------------------------------------------------------------------
__global__ __launch_bounds__(256) void dequant_kernel(
    const float* __restrict__ Wp, const float* __restrict__ E,
    unsigned short* __restrict__ Wt, int NO) {
    __shared__ float En[32 * 16];
    const int tid = threadIdx.x;
    const int ki0 = blockIdx.x * 32;
    const int o0 = blockIdx.y * 32;
    const int n0 = blockIdx.z * 32;
    const int o = tid >> 3;
    const int k4 = tid & 7;

#pragma unroll
    for (int t = 0; t < 2; ++t) {
        const int id = t * 256 + tid;
        En[id] = E[(n0 + (id >> 4)) * EDIM + (id & 15)];
    }
    __syncthreads();

    f32x4 w[EDIM];
#pragma unroll
    for (int e = 0; e < EDIM; ++e) {
        f32x4 v;
#pragma unroll
        for (int j = 0; j < 4; ++j)
            v[j] = Wp[(size_t)(e * KI + ki0 + k4 * 4 + j) * NO + o0 + o];
        w[e] = v;
    }

    const size_t wt_base = ((size_t)n0 * NO + (o0 + o)) * KI + ki0 + k4 * 4;
#pragma unroll 4
    for (int nl = 0; nl < 32; ++nl) {
        f32x4 a = {0.f, 0.f, 0.f, 0.f};
#pragma unroll
        for (int e = 0; e < EDIM; ++e) a += w[e] * En[nl * EDIM + e];
        union { unsigned short u[4]; uint2 v; } pk;
#pragma unroll
        for (int j = 0; j < 4; ++j) pk.u[j] = f2h(a[j]);
        *(uint2*)&Wt[wt_base + (size_t)nl * NO * KI] = pk.v;
    }
}

// ---------------------------------------------------------------------------
// Gate per-node GEMM (merged z+r): M=64(b), N=128(o), K=384.
// LDS-FREE / BARRIER-FREE: A-frags and W-frags both direct global->VGPR
// (A-frag redundancy across the 4 waves is served by L1/L2; W rows are
// wave-private). All 12 k-windows fully unrolled -> static offsets, loads
// pipeline under vmcnt with no sync points.
// ---------------------------------------------------------------------------
__global__ __launch_bounds__(256) void pernode_gate_kernel(
    const unsigned short* __restrict__ TX0,
    const unsigned short* __restrict__ TS0,
    const unsigned short* __restrict__ TX1,
    const unsigned short* __restrict__ TS1,
    const unsigned short* __restrict__ TX2,
    const unsigned short* __restrict__ TS2,
    const unsigned short* __restrict__ Wt, const float* __restrict__ E,
    const float* __restrict__ bp, const float* __restrict__ state,
    unsigned short* __restrict__ rbuf, unsigned short* __restrict__ ts0_out) {
    const int n = blockIdx.x;
    const int tid = threadIdx.x;
    const int wave = tid >> 6;
    const int lane = tid & 63;
    const int l15 = lane & 15;
    const int quad = lane >> 4;
    const int wn = wave * 32;

    float bias[2];
#pragma unroll
    for (int ni = 0; ni < 2; ++ni) {
        float bv = 0.f;
#pragma unroll
        for (int e = 0; e < EDIM; ++e)
            bv += E[n * EDIM + e] * bp[e * 128 + wn + ni * 16 + l15];
        bias[ni] = bv;
    }

    f32x4 acc[4][2] = {};

    // per-lane A row bases (row = mi*16+l15 within each plane), k-chunk = quad
    const unsigned short* planes[6] = {
        TX0 + (size_t)n * GNH, TS0 + (size_t)n * GNH,
        TX1 + (size_t)n * GNH, TS1 + (size_t)n * GNH,
        TX2 + (size_t)n * GNH, TS2 + (size_t)n * GNH};
    const unsigned short* wrow0 = Wt + ((size_t)n * 128 + wn + l15) * KI;
    const unsigned short* wrow1 = Wt + ((size_t)n * 128 + wn + 16 + l15) * KI;

#pragma unroll
    for (int s = 0; s < 3; ++s) {
#pragma unroll
        for (int ks = 0; ks < 4; ++ks) {
            const int kseg = ks * 4 + quad;  // 0..15 within this s-slot
            const unsigned short* plane = planes[s * 2 + (kseg >> 3)];
            const int kc = (kseg & 7) * 8;
            half8_t b[2];
            b[0] = *(const half8_t*)&wrow0[s * 128 + kseg * 8];
            b[1] = *(const half8_t*)&wrow1[s * 128 + kseg * 8];
#pragma unroll
            for (int mi = 0; mi < 4; ++mi) {
                const half8_t a =
                    *(const half8_t*)&plane[(mi * 16 + l15) * 64 + kc];
#pragma unroll
                for (int ni = 0; ni < 2; ++ni)
                    acc[mi][ni] = __builtin_amdgcn_mfma_f32_16x16x32_f16(
                        a, b[ni], acc[mi][ni], 0, 0, 0);
            }
        }
    }

#pragma unroll
    for (int mi = 0; mi < 4; ++mi) {
#pragma unroll
        for (int r = 0; r < 4; ++r) {
            const int b_g = mi * 16 + quad * 4 + r;
#pragma unroll
            for (int ni = 0; ni < 2; ++ni) {
                const int o_g = wn + ni * 16 + l15;
                const float v = sigmoidf_(acc[mi][ni][r] + bias[ni]);
                if (o_g < 64) {  // z -> candidate state slice
                    const float sv =
                        state[((size_t)b_g * N_NODES + n) * 64 + o_g];
                    ts0_out[(size_t)n * GNH + b_g * 64 + o_g] = f2h(v * sv);
                } else {  // r
                    rbuf[((size_t)n * B_SZ + b_g) * 64 + (o_g - 64)] = f2h(v);
                }
            }
        }
    }
}

// ---------------------------------------------------------------------------
// Update per-node GEMM: out = r*state + (1-r)*tanh(acc+bias). N=64.
// LDS-free / barrier-free (same scheme as gate).
// ---------------------------------------------------------------------------
__global__ __launch_bounds__(256) void pernode_upd_kernel(
    const unsigned short* __restrict__ TX0,
    const unsigned short* __restrict__ TS0,
    const unsigned short* __restrict__ TX1,
    const unsigned short* __restrict__ TS1,
    const unsigned short* __restrict__ TX2,
    const unsigned short* __restrict__ TS2,
    const unsigned short* __restrict__ Wt, const float* __restrict__ E,
    const float* __restrict__ bp, const float* __restrict__ state,
    const unsigned short* __restrict__ rbuf, float* __restrict__ out) {
    const int n = blockIdx.x;
    const int tid = threadIdx.x;
    const int wave = tid >> 6;
    const int lane = tid & 63;
    const int l15 = lane & 15;
    const int quad = lane >> 4;
    const int wn = wave * 16;
    const int o_g = wn + l15;

    float bias = 0.f;
#pragma unroll
    for (int e = 0; e < EDIM; ++e)
        bias += E[n * EDIM + e] * bp[e * 64 + o_g];

    f32x4 acc[4] = {};

    const unsigned short* planes[6] = {
        TX0 + (size_t)n * GNH, TS0 + (size_t)n * GNH,
        TX1 + (size_t)n * GNH, TS1 + (size_t)n * GNH,
        TX2 + (size_t)n * GNH, TS2 + (size_t)n * GNH};
    const unsigned short* wrow = Wt + ((size_t)n * 64 + o_g) * KI;

#pragma unroll
    for (int s = 0; s < 3; ++s) {
#pragma unroll
        for (int ks = 0; ks < 4; ++ks) {
            const int kseg = ks * 4 + quad;
            const unsigned short* plane = planes[s * 2 + (kseg >> 3)];
            const int kc = (kseg & 7) * 8;
            const half8_t b = *(const half8_t*)&wrow[s * 128 + kseg * 8];
#pragma unroll
            for (int mi = 0; mi < 4; ++mi) {
                const half8_t a =
                    *(const half8_t*)&plane[(mi * 16 + l15) * 64 + kc];
                acc[mi] = __builtin_amdgcn_mfma_f32_16x16x32_f16(a, b, acc[mi],
                                                                 0, 0, 0);
            }
        }
    }

#pragma unroll
    for (int mi = 0; mi < 4; ++mi) {
#pragma unroll
        for (int r = 0; r < 4; ++r) {
            const int b_g = mi * 16 + quad * 4 + r;
            const float hc = tanhf(acc[mi][r] + bias);
            const float rr = h2f(rbuf[((size_t)n * B_SZ + b_g) * 64 + o_g]);
            const float sv = state[((size_t)b_g * N_NODES + n) * 64 + o_g];
            out[((size_t)b_g * N_NODES + n) * 64 + o_g] =
                rr * sv + (1.f - rr) * hc;
        }
    }
}

// ---------------------------------------------------------------------------
extern "C" void kernel_launch(void* const* d_in, const int* in_sizes, int n_in,
                              void* d_out, int out_size, void* d_ws,
                              size_t ws_size, hipStream_t stream) {
    const float* x = (const float*)d_in[0];
    const float* state = (const float*)d_in[1];
    const float* E = (const float*)d_in[2];
    const float* gW = (const float*)d_in[3];  // (16,3,128,128)
    const float* gb = (const float*)d_in[4];  // (16,128)
    const float* uW = (const float*)d_in[5];  // (16,3,128,64)
    const float* ub = (const float*)d_in[6];  // (16,64)
    float* out = (float*)d_out;

    char* ws = (char*)d_ws;
    unsigned short* Ah = (unsigned short*)ws;                 //  2.10 MB
    unsigned short* AhT = (unsigned short*)(ws + 2097152);    //  2.10 MB
    unsigned short* S2h = (unsigned short*)(ws + 4194304);    //  2.10 MB
    unsigned short* TX0 = (unsigned short*)(ws + 6291456);    //  8.39 MB each
    unsigned short* TS0 = (unsigned short*)(ws + 14680064);
    unsigned short* TX0T = (unsigned short*)(ws + 23068672);
    unsigned short* TS0T = (unsigned short*)(ws + 31457280);
    unsigned short* TX1 = (unsigned short*)(ws + 39845888);
    unsigned short* TS1 = (unsigned short*)(ws + 48234496);
    unsigned short* TX2 = (unsigned short*)(ws + 56623104);
    unsigned short* TS2 = (unsigned short*)(ws + 65011712);
    unsigned short* Wt = (unsigned short*)(ws + 73400320);    // 100.66 MB
    unsigned short* rbuf = (unsigned short*)(ws + 174063616); //   8.39 MB
    // total 182.4 MB (ws = 256 MB)

    compute_A_kernel<<<N_NODES, 256, 0, stream>>>(E, Ah);
    build_T0_all_kernel<<<dim3(16, 64), 256, 0, stream>>>(x, state, TX0, TS0,
                                                          TX0T, TS0T);
    transpose16_kernel<<<dim3(16, 16), 256, 0, stream>>>(Ah, AhT, N_NODES);
    gemm_s2_kernel<<<dim3(16, 16), 256, 0, stream>>>(Ah, AhT, S2h);

    // --- avwgcn #1 (gate): ggemm, then dequant (Wt stays L3-hot), pernode ---
    gemm_graph_kernel<<<1024, 256, 0, stream>>>(
        Ah, S2h, TX0T, TS0T, TX1, TS1, TX2, TS2, 32, 8);
    dequant_kernel<<<dim3(12, 4, 32), 256, 0, stream>>>(gW, E, Wt, 128);
    pernode_gate_kernel<<<N_NODES, 256, 0, stream>>>(
        TX0, TS0, TX1, TS1, TX2, TS2, Wt, E, gb, state, rbuf, TS0);
    // regenerate TS0T (coalesced) from the new candidate state slice
    transpose16_kernel<<<dim3(16, 64), 256, 0, stream>>>(TS0, TS0T, GNH);

    // --- avwgcn #2 (update): x-half of T1/T2 unchanged — S columns only ---
    gemm_graph_kernel<<<512, 256, 0, stream>>>(
        Ah, S2h, TX0T, TS0T, TX1, TS1, TX2, TS2, 0, 4);
    dequant_kernel<<<dim3(12, 2, 32), 256, 0, stream>>>(uW, E, Wt, 64);
    pernode_upd_kernel<<<N_NODES, 256, 0, stream>>>(
        TX0, TS0, TX1, TS1, TX2, TS2, Wt, E, ub, state, rbuf, out);
}

// Round 14
// 306.716 us; speedup vs baseline: 1.0564x; 1.0564x over previous
//
#include <hip/hip_runtime.h>
#include <math.h>

#define N_NODES 1024
#define B_SZ 64
#define GNH 4096     // half-width: b*64+c layout for X or S plane
#define KI 384       // 3*128
#define EDIM 16

typedef _Float16 half8_t __attribute__((ext_vector_type(8)));
typedef float f32x4 __attribute__((ext_vector_type(4)));

__device__ __forceinline__ unsigned short f2h(float f) {
    _Float16 h = (_Float16)f;
    return *(unsigned short*)&h;
}
__device__ __forceinline__ float h2f(unsigned short u) {
    _Float16 h = *(_Float16*)&u;
    return (float)h;
}
__device__ __forceinline__ float sigmoidf_(float v) {
    return 1.f / (1.f + __expf(-v));
}
// async global->LDS, 16B per lane; lds base must be wave-uniform.
__device__ __forceinline__ void load_lds16(const void* g, void* l) {
    __builtin_amdgcn_global_load_lds(
        (const __attribute__((address_space(1))) void*)g,
        (__attribute__((address_space(3))) void*)l, 16, 0, 0);
}

// ---------------------------------------------------------------------------
// A = softmax(relu(E E^T)) row-wise -> Ah[n][m]  (fp16, coalesced only)
// ---------------------------------------------------------------------------
__global__ __launch_bounds__(256) void compute_A_kernel(
    const float* __restrict__ E, unsigned short* __restrict__ Ah) {
    __shared__ float red[256];
    const int tid = threadIdx.x;
    const int n = blockIdx.x;
    float en[EDIM];
#pragma unroll
    for (int e = 0; e < EDIM; ++e) en[e] = E[n * EDIM + e];
    float logit[4], lmax = -1e30f;
#pragma unroll
    for (int j = 0; j < 4; ++j) {
        const int m = tid + j * 256;
        float d = 0.f;
#pragma unroll
        for (int e = 0; e < EDIM; ++e) d += en[e] * E[m * EDIM + e];
        d = fmaxf(d, 0.f);
        logit[j] = d;
        lmax = fmaxf(lmax, d);
    }
    red[tid] = lmax;
    __syncthreads();
    for (int s = 128; s > 0; s >>= 1) {
        if (tid < s) red[tid] = fmaxf(red[tid], red[tid + s]);
        __syncthreads();
    }
    lmax = red[0];
    __syncthreads();
    float ex[4], lsum = 0.f;
#pragma unroll
    for (int j = 0; j < 4; ++j) {
        ex[j] = __expf(logit[j] - lmax);
        lsum += ex[j];
    }
    red[tid] = lsum;
    __syncthreads();
    for (int s = 128; s > 0; s >>= 1) {
        if (tid < s) red[tid] += red[tid + s];
        __syncthreads();
    }
    const float inv = 1.f / red[0];
#pragma unroll
    for (int j = 0; j < 4; ++j)
        Ah[n * N_NODES + tid + j * 256] = f2h(ex[j] * inv);
}

// ---------------------------------------------------------------------------
// Fused build: TX0/TS0 (row-major, direct) + TX0T/TS0T (via LDS transpose).
// grid (16 n-tiles, 64 b).
// ---------------------------------------------------------------------------
__global__ __launch_bounds__(256) void build_T0_all_kernel(
    const float* __restrict__ x, const float* __restrict__ state,
    unsigned short* __restrict__ TX0, unsigned short* __restrict__ TS0,
    unsigned short* __restrict__ TX0T, unsigned short* __restrict__ TS0T) {
    __shared__ unsigned short Lx[64 * 72];   // [c][nl], pad 72 (16B rows)
    __shared__ unsigned short Lss[64 * 72];
    const int tid = threadIdx.x;
    const int n0 = blockIdx.x * 64;
    const int b = blockIdx.y;
#pragma unroll
    for (int t = 0; t < 16; ++t) {
        const int id = t * 256 + tid;
        const int nl = id >> 6;
        const int c = id & 63;
        const float xv = x[((size_t)b * N_NODES + n0 + nl) * 64 + c];
        const float sv = state[((size_t)b * N_NODES + n0 + nl) * 64 + c];
        const unsigned short xh = f2h(xv), sh = f2h(sv);
        TX0[(size_t)(n0 + nl) * GNH + b * 64 + c] = xh;
        TS0[(size_t)(n0 + nl) * GNH + b * 64 + c] = sh;
        Lx[c * 72 + nl] = xh;
        Lss[c * 72 + nl] = sh;
    }
    __syncthreads();
#pragma unroll
    for (int t = 0; t < 2; ++t) {
        const int id = t * 256 + tid;
        const int c = id >> 3;
        const int n8 = id & 7;
        uint4 xv = *(const uint4*)&Lx[c * 72 + n8 * 8];
        uint4 sv = *(const uint4*)&Lss[c * 72 + n8 * 8];
        *(uint4*)&TX0T[(size_t)(b * 64 + c) * N_NODES + n0 + n8 * 8] = xv;
        *(uint4*)&TS0T[(size_t)(b * 64 + c) * N_NODES + n0 + n8 * 8] = sv;
    }
}

// ---------------------------------------------------------------------------
// Generic fp16 transpose: dst[c][1024] = src[r][W], 64x64 tiles.
// ---------------------------------------------------------------------------
__global__ __launch_bounds__(256) void transpose16_kernel(
    const unsigned short* __restrict__ src, unsigned short* __restrict__ dst,
    int W) {
    __shared__ unsigned short Ls[64 * 72];
    const int tid = threadIdx.x;
    const int r0 = blockIdx.x * 64;
    const int c0 = blockIdx.y * 64;
#pragma unroll
    for (int t = 0; t < 2; ++t) {
        const int id = t * 256 + tid;
        const int row = id >> 3;
        const int c8 = id & 7;
        uint4 v = *(const uint4*)&src[(size_t)(r0 + row) * W + c0 + c8 * 8];
        const unsigned short* vp = (const unsigned short*)&v;
#pragma unroll
        for (int j = 0; j < 8; ++j) Ls[(c8 * 8 + j) * 72 + row] = vp[j];
    }
    __syncthreads();
#pragma unroll
    for (int t = 0; t < 2; ++t) {
        const int id = t * 256 + tid;
        const int c = id >> 3;
        const int r8 = id & 7;
        uint4 v = *(const uint4*)&Ls[c * 72 + r8 * 8];
        *(uint4*)&dst[(size_t)(c0 + c) * N_NODES + r0 + r8 * 8] = v;
    }
}

// ---------------------------------------------------------------------------
// S2h[n][m] = 2 * sum_k Ah[n][k]*AhT[m][k] - (n==m)   (S2 = 2A^2 - I)
// ---------------------------------------------------------------------------
__global__ __launch_bounds__(256) void gemm_s2_kernel(
    const unsigned short* __restrict__ Ah,
    const unsigned short* __restrict__ AhT, unsigned short* __restrict__ S2h) {
    __shared__ unsigned short As[64 * 64];
    __shared__ unsigned short Bs[64 * 64];
    const int tid = threadIdx.x;
    const int wave = tid >> 6;
    const int lane = tid & 63;
    const int l15 = lane & 15;
    const int quad = lane >> 4;
    const int n0 = blockIdx.x * 64;
    const int m0 = blockIdx.y * 64;
    const int wn = wave * 16;
    const int lr = lane >> 3;
    const int lsw = (lane & 7) ^ lr;

    f32x4 acc[4] = {};
    for (int k0 = 0; k0 < N_NODES; k0 += 64) {
#pragma unroll
        for (int i = 0; i < 2; ++i) {
            const int rbase = (wave * 2 + i) * 8;
            load_lds16(&Ah[(size_t)(n0 + rbase + lr) * N_NODES + k0 + lsw * 8],
                       &As[rbase * 64]);
            load_lds16(&AhT[(size_t)(m0 + rbase + lr) * N_NODES + k0 + lsw * 8],
                       &Bs[rbase * 64]);
        }
        __syncthreads();
#pragma unroll
        for (int ks = 0; ks < 2; ++ks) {
            const int slot = ((ks * 4 + quad) ^ (l15 & 7)) * 8;
            const half8_t b = *(const half8_t*)&Bs[(wn + l15) * 64 + slot];
#pragma unroll
            for (int mi = 0; mi < 4; ++mi) {
                const half8_t a = *(const half8_t*)&As[(mi * 16 + l15) * 64 + slot];
                acc[mi] =
                    __builtin_amdgcn_mfma_f32_16x16x32_f16(a, b, acc[mi], 0, 0, 0);
            }
        }
        __syncthreads();
    }
#pragma unroll
    for (int mi = 0; mi < 4; ++mi) {
#pragma unroll
        for (int r = 0; r < 4; ++r) {
            const int n_g = n0 + mi * 16 + quad * 4 + r;
            const int m_g = m0 + wn + l15;
            const float v = 2.f * acc[mi][r] - (n_g == m_g ? 1.f : 0.f);
            S2h[(size_t)n_g * N_NODES + m_g] = f2h(v);
        }
    }
}

// ---------------------------------------------------------------------------
// Graph GEMM: 128x128 tile, BK=64, rows [A;S2]; cols X/S planes. 32 KB LDS.
// 1D grid with XCD-aware swizzle: xcd = id&7 owns a contiguous slab of
// column tiles (colsPerXcd) x all 16 row tiles -> B slab stays in L2.
// ---------------------------------------------------------------------------
__global__ __launch_bounds__(256) void gemm_graph_kernel(
    const unsigned short* __restrict__ Ah,
    const unsigned short* __restrict__ S2h,
    const unsigned short* __restrict__ BTX,
    const unsigned short* __restrict__ BTS,
    unsigned short* __restrict__ T1X, unsigned short* __restrict__ T1S,
    unsigned short* __restrict__ T2X, unsigned short* __restrict__ T2S,
    int ysplit, int colsPerXcd) {
    __shared__ union {
        struct {
            unsigned short As[128 * 64];  // [m-local][k] swizzled (16 KB)
            unsigned short Bs[128 * 64];  // [col-local][k] swizzled (16 KB)
        } s;
        unsigned short Cs[64 * 136];      // epilogue repack (17.4 KB)
    } lds;
    const int tid = threadIdx.x;
    const int wave = tid >> 6;
    const int lane = tid & 63;
    const int l15 = lane & 15;
    const int quad = lane >> 4;
    const int wm = (wave >> 1) * 64;
    const int wn = (wave & 1) * 64;
    // XCD-locality swizzle
    const int id = blockIdx.x;
    const int xcd = id & 7;
    const int j = id >> 3;
    const int mrow0 = (j & 15) * 128;
    const int ytile = xcd * colsPerXcd + (j >> 4);
    const bool isA = mrow0 < N_NODES;
    const unsigned short* Asrc =
        (isA ? Ah : S2h) + (size_t)(mrow0 & 1023) * N_NODES;
    const bool isX = ytile < ysplit;
    const int col0 = (isX ? ytile : ytile - ysplit) * 128;
    const unsigned short* Bsrc =
        (isX ? BTX : BTS) + (size_t)col0 * N_NODES;
    unsigned short* OUT =
        (isA ? (isX ? T1X : T1S) : (isX ? T2X : T2S)) +
        (size_t)(mrow0 & 1023) * GNH + col0;
    const int lr = lane >> 3;
    const int lsw = (lane & 7) ^ lr;

    f32x4 acc[4][4] = {};

    for (int k0 = 0; k0 < N_NODES; k0 += 64) {
#pragma unroll
        for (int i = 0; i < 4; ++i) {
            const int rbase = (wave * 4 + i) * 8;
            load_lds16(&Asrc[(size_t)(rbase + lr) * N_NODES + k0 + lsw * 8],
                       &lds.s.As[rbase * 64]);
        }
#pragma unroll
        for (int i = 0; i < 4; ++i) {
            const int rbase = (wave * 4 + i) * 8;
            load_lds16(&Bsrc[(size_t)(rbase + lr) * N_NODES + k0 + lsw * 8],
                       &lds.s.Bs[rbase * 64]);
        }
        __syncthreads();
#pragma unroll
        for (int ks = 0; ks < 2; ++ks) {
            const int slot = ((ks * 4 + quad) ^ (l15 & 7)) * 8;
            half8_t a[4], b[4];
#pragma unroll
            for (int mi = 0; mi < 4; ++mi)
                a[mi] = *(const half8_t*)&lds.s
                             .As[(wm + mi * 16 + l15) * 64 + slot];
#pragma unroll
            for (int ni = 0; ni < 4; ++ni)
                b[ni] = *(const half8_t*)&lds.s
                             .Bs[(wn + ni * 16 + l15) * 64 + slot];
#pragma unroll
            for (int mi = 0; mi < 4; ++mi)
#pragma unroll
                for (int ni = 0; ni < 4; ++ni)
                    acc[mi][ni] = __builtin_amdgcn_mfma_f32_16x16x32_f16(
                        a[mi], b[ni], acc[mi][ni], 0, 0, 0);
        }
        __syncthreads();
    }

    // epilogue: two 64-row passes through 64x136 Cs -> coalesced uint4 stores
#pragma unroll
    for (int p = 0; p < 2; ++p) {
        if (p) __syncthreads();
        if ((wave >> 1) == p) {
#pragma unroll
            for (int mi = 0; mi < 4; ++mi)
#pragma unroll
                for (int ni = 0; ni < 4; ++ni)
#pragma unroll
                    for (int r = 0; r < 4; ++r) {
                        const int row = mi * 16 + quad * 4 + r;  // 0..63
                        const int col = wn + ni * 16 + l15;
                        lds.Cs[row * 136 + col] = f2h(acc[mi][ni][r]);
                    }
        }
        __syncthreads();
#pragma unroll
        for (int i = 0; i < 4; ++i) {
            const int id2 = i * 256 + tid;  // 0..1023
            const int row = id2 >> 4;       // 0..63
            const int c8 = id2 & 15;
            uint4 cv = *(const uint4*)&lds.Cs[row * 136 + c8 * 8];
            *(uint4*)&OUT[(size_t)(p * 64 + row) * GNH + c8 * 8] = cv;
        }
    }
}

// ---------------------------------------------------------------------------
// Dequant: Wt[n][o][ki] = sum_e E[n,e]*Wp[e][ki][o]  (fp16, k-contig)
// ---------------------------------------------------------------------------
__global__ __launch_bounds__(256) void dequant_kernel(
    const float* __restrict__ Wp, const float* __restrict__ E,
    unsigned short* __restrict__ Wt, int NO) {
    __shared__ float En[32 * 16];
    const int tid = threadIdx.x;
    const int ki0 = blockIdx.x * 32;
    const int o0 = blockIdx.y * 32;
    const int n0 = blockIdx.z * 32;
    const int o = tid >> 3;
    const int k4 = tid & 7;

#pragma unroll
    for (int t = 0; t < 2; ++t) {
        const int id = t * 256 + tid;
        En[id] = E[(n0 + (id >> 4)) * EDIM + (id & 15)];
    }
    __syncthreads();

    f32x4 w[EDIM];
#pragma unroll
    for (int e = 0; e < EDIM; ++e) {
        f32x4 v;
#pragma unroll
        for (int j = 0; j < 4; ++j)
            v[j] = Wp[(size_t)(e * KI + ki0 + k4 * 4 + j) * NO + o0 + o];
        w[e] = v;
    }

    const size_t wt_base = ((size_t)n0 * NO + (o0 + o)) * KI + ki0 + k4 * 4;
#pragma unroll 4
    for (int nl = 0; nl < 32; ++nl) {
        f32x4 a = {0.f, 0.f, 0.f, 0.f};
#pragma unroll
        for (int e = 0; e < EDIM; ++e) a += w[e] * En[nl * EDIM + e];
        union { unsigned short u[4]; uint2 v; } pk;
#pragma unroll
        for (int j = 0; j < 4; ++j) pk.u[j] = f2h(a[j]);
        *(uint2*)&Wt[wt_base + (size_t)nl * NO * KI] = pk.v;
    }
}

// ---------------------------------------------------------------------------
// Gate per-node GEMM (merged z+r): M=64(b), N=128(o), K=384.
// W fragments direct global->VGPR; X planes staged (16 KB LDS). rbuf fp16.
// ---------------------------------------------------------------------------
__global__ __launch_bounds__(256) void pernode_gate_kernel(
    const unsigned short* __restrict__ TX0,
    const unsigned short* __restrict__ TS0,
    const unsigned short* __restrict__ TX1,
    const unsigned short* __restrict__ TS1,
    const unsigned short* __restrict__ TX2,
    const unsigned short* __restrict__ TS2,
    const unsigned short* __restrict__ Wt, const float* __restrict__ E,
    const float* __restrict__ bp, const float* __restrict__ state,
    unsigned short* __restrict__ rbuf, unsigned short* __restrict__ ts0_out) {
    __shared__ unsigned short XsX[64 * 64];  // [b][kseg 0..7] swizzled
    __shared__ unsigned short XsS[64 * 64];  // [b][kseg 8..15] swizzled
    const int n = blockIdx.x;
    const int tid = threadIdx.x;
    const int wave = tid >> 6;
    const int lane = tid & 63;
    const int l15 = lane & 15;
    const int quad = lane >> 4;
    const int wn = wave * 32;
    const int lr = lane >> 3;
    const int lsw = (lane & 7) ^ lr;

    float bias[2];
#pragma unroll
    for (int ni = 0; ni < 2; ++ni) {
        float bv = 0.f;
#pragma unroll
        for (int e = 0; e < EDIM; ++e)
            bv += E[n * EDIM + e] * bp[e * 128 + wn + ni * 16 + l15];
        bias[ni] = bv;
    }

    f32x4 acc[4][2] = {};

    const unsigned short* TXs[3] = {TX0, TX1, TX2};
    const unsigned short* TSs[3] = {TS0, TS1, TS2};
    const unsigned short* wrow0 = Wt + ((size_t)n * 128 + wn + l15) * KI;
    const unsigned short* wrow1 = Wt + ((size_t)n * 128 + wn + 16 + l15) * KI;

    for (int s = 0; s < 3; ++s) {
        const unsigned short* xs = TXs[s] + (size_t)n * GNH;
        const unsigned short* ss = TSs[s] + (size_t)n * GNH;
#pragma unroll
        for (int i = 0; i < 2; ++i) {
            const int slab = wave * 2 + i;  // 8 slabs of 8 b-rows
            load_lds16(xs + (slab * 8 + lr) * 64 + lsw * 8, &XsX[slab * 512]);
            load_lds16(ss + (slab * 8 + lr) * 64 + lsw * 8, &XsS[slab * 512]);
        }
        __syncthreads();
#pragma unroll
        for (int ks = 0; ks < 4; ++ks) {
            const int kseg = ks * 4 + quad;  // 0..15
            half8_t b[2];
            b[0] = *(const half8_t*)&wrow0[s * 128 + kseg * 8];
            b[1] = *(const half8_t*)&wrow1[s * 128 + kseg * 8];
            const unsigned short* plane = (kseg < 8) ? XsX : XsS;
            const int aslot = ((kseg & 7) ^ (l15 & 7)) * 8;
#pragma unroll
            for (int mi = 0; mi < 4; ++mi) {
                const half8_t a =
                    *(const half8_t*)&plane[(mi * 16 + l15) * 64 + aslot];
#pragma unroll
                for (int ni = 0; ni < 2; ++ni)
                    acc[mi][ni] = __builtin_amdgcn_mfma_f32_16x16x32_f16(
                        a, b[ni], acc[mi][ni], 0, 0, 0);
            }
        }
        __syncthreads();
    }

#pragma unroll
    for (int mi = 0; mi < 4; ++mi) {
#pragma unroll
        for (int r = 0; r < 4; ++r) {
            const int b_g = mi * 16 + quad * 4 + r;
#pragma unroll
            for (int ni = 0; ni < 2; ++ni) {
                const int o_g = wn + ni * 16 + l15;
                const float v = sigmoidf_(acc[mi][ni][r] + bias[ni]);
                if (o_g < 64) {  // z -> candidate state slice
                    const float sv =
                        state[((size_t)b_g * N_NODES + n) * 64 + o_g];
                    ts0_out[(size_t)n * GNH + b_g * 64 + o_g] = f2h(v * sv);
                } else {  // r
                    rbuf[((size_t)n * B_SZ + b_g) * 64 + (o_g - 64)] = f2h(v);
                }
            }
        }
    }
}

// ---------------------------------------------------------------------------
// Update per-node GEMM: out = r*state + (1-r)*tanh(acc+bias). N=64. 16 KB LDS.
// ---------------------------------------------------------------------------
__global__ __launch_bounds__(256) void pernode_upd_kernel(
    const unsigned short* __restrict__ TX0,
    const unsigned short* __restrict__ TS0,
    const unsigned short* __restrict__ TX1,
    const unsigned short* __restrict__ TS1,
    const unsigned short* __restrict__ TX2,
    const unsigned short* __restrict__ TS2,
    const unsigned short* __restrict__ Wt, const float* __restrict__ E,
    const float* __restrict__ bp, const float* __restrict__ state,
    const unsigned short* __restrict__ rbuf, float* __restrict__ out) {
    __shared__ unsigned short XsX[64 * 64];
    __shared__ unsigned short XsS[64 * 64];
    const int n = blockIdx.x;
    const int tid = threadIdx.x;
    const int wave = tid >> 6;
    const int lane = tid & 63;
    const int l15 = lane & 15;
    const int quad = lane >> 4;
    const int wn = wave * 16;
    const int o_g = wn + l15;
    const int lr = lane >> 3;
    const int lsw = (lane & 7) ^ lr;

    float bias = 0.f;
#pragma unroll
    for (int e = 0; e < EDIM; ++e)
        bias += E[n * EDIM + e] * bp[e * 64 + o_g];

    f32x4 acc[4] = {};

    const unsigned short* TXs[3] = {TX0, TX1, TX2};
    const unsigned short* TSs[3] = {TS0, TS1, TS2};
    const unsigned short* wrow = Wt + ((size_t)n * 64 + o_g) * KI;

    for (int s = 0; s < 3; ++s) {
        const unsigned short* xs = TXs[s] + (size_t)n * GNH;
        const unsigned short* ss = TSs[s] + (size_t)n * GNH;
#pragma unroll
        for (int i = 0; i < 2; ++i) {
            const int slab = wave * 2 + i;
            load_lds16(xs + (slab * 8 + lr) * 64 + lsw * 8, &XsX[slab * 512]);
            load_lds16(ss + (slab * 8 + lr) * 64 + lsw * 8, &XsS[slab * 512]);
        }
        __syncthreads();
#pragma unroll
        for (int ks = 0; ks < 4; ++ks) {
            const int kseg = ks * 4 + quad;
            const half8_t b = *(const half8_t*)&wrow[s * 128 + kseg * 8];
            const unsigned short* plane = (kseg < 8) ? XsX : XsS;
            const int aslot = ((kseg & 7) ^ (l15 & 7)) * 8;
#pragma unroll
            for (int mi = 0; mi < 4; ++mi) {
                const half8_t a =
                    *(const half8_t*)&plane[(mi * 16 + l15) * 64 + aslot];
                acc[mi] = __builtin_amdgcn_mfma_f32_16x16x32_f16(a, b, acc[mi],
                                                                 0, 0, 0);
            }
        }
        __syncthreads();
    }

#pragma unroll
    for (int mi = 0; mi < 4; ++mi) {
#pragma unroll
        for (int r = 0; r < 4; ++r) {
            const int b_g = mi * 16 + quad * 4 + r;
            const float hc = tanhf(acc[mi][r] + bias);
            const float rr = h2f(rbuf[((size_t)n * B_SZ + b_g) * 64 + o_g]);
            const float sv = state[((size_t)b_g * N_NODES + n) * 64 + o_g];
            out[((size_t)b_g * N_NODES + n) * 64 + o_g] =
                rr * sv + (1.f - rr) * hc;
        }
    }
}

// ---------------------------------------------------------------------------
extern "C" void kernel_launch(void* const* d_in, const int* in_sizes, int n_in,
                              void* d_out, int out_size, void* d_ws,
                              size_t ws_size, hipStream_t stream) {
    const float* x = (const float*)d_in[0];
    const float* state = (const float*)d_in[1];
    const float* E = (const float*)d_in[2];
    const float* gW = (const float*)d_in[3];  // (16,3,128,128)
    const float* gb = (const float*)d_in[4];  // (16,128)
    const float* uW = (const float*)d_in[5];  // (16,3,128,64)
    const float* ub = (const float*)d_in[6];  // (16,64)
    float* out = (float*)d_out;

    char* ws = (char*)d_ws;
    unsigned short* Ah = (unsigned short*)ws;                 //  2.10 MB
    unsigned short* AhT = (unsigned short*)(ws + 2097152);    //  2.10 MB
    unsigned short* S2h = (unsigned short*)(ws + 4194304);    //  2.10 MB
    unsigned short* TX0 = (unsigned short*)(ws + 6291456);    //  8.39 MB each
    unsigned short* TS0 = (unsigned short*)(ws + 14680064);
    unsigned short* TX0T = (unsigned short*)(ws + 23068672);
    unsigned short* TS0T = (unsigned short*)(ws + 31457280);
    unsigned short* TX1 = (unsigned short*)(ws + 39845888);
    unsigned short* TS1 = (unsigned short*)(ws + 48234496);
    unsigned short* TX2 = (unsigned short*)(ws + 56623104);
    unsigned short* TS2 = (unsigned short*)(ws + 65011712);
    unsigned short* Wt = (unsigned short*)(ws + 73400320);    // 100.66 MB
    unsigned short* rbuf = (unsigned short*)(ws + 174063616); //   8.39 MB
    // total 182.4 MB (ws = 256 MB)

    compute_A_kernel<<<N_NODES, 256, 0, stream>>>(E, Ah);
    build_T0_all_kernel<<<dim3(16, 64), 256, 0, stream>>>(x, state, TX0, TS0,
                                                          TX0T, TS0T);
    transpose16_kernel<<<dim3(16, 16), 256, 0, stream>>>(Ah, AhT, N_NODES);
    gemm_s2_kernel<<<dim3(16, 16), 256, 0, stream>>>(Ah, AhT, S2h);

    // --- avwgcn #1 (gate): ggemm, then dequant (Wt stays L3-hot), pernode ---
    gemm_graph_kernel<<<1024, 256, 0, stream>>>(
        Ah, S2h, TX0T, TS0T, TX1, TS1, TX2, TS2, 32, 8);
    dequant_kernel<<<dim3(12, 4, 32), 256, 0, stream>>>(gW, E, Wt, 128);
    pernode_gate_kernel<<<N_NODES, 256, 0, stream>>>(
        TX0, TS0, TX1, TS1, TX2, TS2, Wt, E, gb, state, rbuf, TS0);
    // regenerate TS0T (coalesced) from the new candidate state slice
    transpose16_kernel<<<dim3(16, 64), 256, 0, stream>>>(TS0, TS0T, GNH);

    // --- avwgcn #2 (update): x-half of T1/T2 unchanged — S columns only ---
    gemm_graph_kernel<<<512, 256, 0, stream>>>(
        Ah, S2h, TX0T, TS0T, TX1, TS1, TX2, TS2, 0, 4);
    dequant_kernel<<<dim3(12, 2, 32), 256, 0, stream>>>(uW, E, Wt, 64);
    pernode_upd_kernel<<<N_NODES, 256, 0, stream>>>(
        TX0, TS0, TX1, TS1, TX2, TS2, Wt, E, ub, state, rbuf, out);
}